// Round 3
// 600.285 us; speedup vs baseline: 1.0663x; 1.0663x over previous
//
#include <hip/hip_runtime.h>
#include <hip/hip_bf16.h>

// Shapes (fixed by setup_inputs): BC=128, H=4, N=1024, d=64, l=16, B=4, C=32,
// C_ch=32, TC=144, r=8. All float tensors are FLOAT32 (per reference).
typedef unsigned short ushort_t;

__device__ __forceinline__ float bf2f(ushort_t u) {
    return __uint_as_float(((unsigned int)u) << 16);
}
__device__ __forceinline__ ushort_t f2bf(float f) {
    __hip_bfloat16 h = __float2bfloat16(f);
    return *reinterpret_cast<ushort_t*>(&h);
}

// ---------------- pq = slots[0] @ W^T, reshaped to [h][l][d] ----------------
// grid = 16 (one block per slot l), 256 threads (j = h*64+d)
__global__ __launch_bounds__(256) void k_pq(const float* __restrict__ slots,
                                            const float* __restrict__ W,
                                            float* __restrict__ pq) {
    int l = blockIdx.x, j = threadIdx.x;
    __shared__ float SL[256];
    SL[j] = slots[l * 256 + j];
    __syncthreads();
    const float4* wr = (const float4*)(W + j * 256);
    float acc = 0.f;
#pragma unroll 8
    for (int g = 0; g < 64; ++g) {
        float4 wv = wr[g];
        const float* sl = &SL[g * 4];
        acc += wv.x * sl[0] + wv.y * sl[1] + wv.z * sl[2] + wv.w * sl[3];
    }
    int h = j >> 6, d = j & 63;
    pq[(h * 16 + l) * 64 + d] = acc;
}

// ---------------- mu_flat[l][c*32+dd], mu_sqnorm[l] ----------------
__global__ void k_mu(const float* __restrict__ mu,
                     const int* __restrict__ cidx,
                     float* __restrict__ mu_flat,
                     float* __restrict__ mu_sq) {
    int l = blockIdx.x;            // 16 blocks
    __shared__ float U[256];       // [c][r] 32x8
    __shared__ float utu[64];
    int t = threadIdx.x;
    {
        int c = t >> 3, r = t & 7;
        U[t] = mu[(l * 144 + cidx[c]) * 8 + r];
    }
    __syncthreads();
#pragma unroll
    for (int i = 0; i < 4; ++i) {
        int e = t + i * 256;
        int c = e >> 5, dd = e & 31;
        float acc = 0.f;
#pragma unroll
        for (int r = 0; r < 8; ++r) acc += U[c * 8 + r] * U[dd * 8 + r];
        mu_flat[l * 1024 + e] = acc;
    }
    if (t < 64) {
        int r = t >> 3, s = t & 7;
        float acc = 0.f;
        for (int c = 0; c < 32; ++c) acc += U[c * 8 + r] * U[c * 8 + s];
        utu[t] = acc;
    }
    __syncthreads();
    if (t == 0) {
        float acc = 0.f;
        for (int i = 0; i < 64; ++i) acc += utu[i] * utu[i];
        mu_sq[l] = acc;
    }
}

// ---------------- dist[bs][l][n] ----------------
// grid = 256: bs = blk>>6, nchunk = blk&63. 256 threads: 16 rows x 16 lanes/row.
// No LDS: mu_flat (64KB) is L2-resident and each float4 read is a 4-way
// intra-wave broadcast, so global reads through L1/L2 are cheap.
__global__ __launch_bounds__(256) void k_dist(const float* __restrict__ Ln,
                                              const float* __restrict__ mu_flat,
                                              const float* __restrict__ mu_sq,
                                              float* __restrict__ dist) {
    int blk = blockIdx.x;
    int nchunk = blk & 63, bs = blk >> 6;
    int t = threadIdx.x;
    int ln = t & 15, rid = t >> 4;
    int n = nchunk * 16 + rid;
    const float4* lr = (const float4*)(Ln + ((size_t)(bs * 1024 + n)) * 1024);
    const float4* mf = (const float4*)mu_flat;
    float lsq = 0.f;
    float cr[16];
#pragma unroll
    for (int l = 0; l < 16; ++l) cr[l] = 0.f;
#pragma unroll 2
    for (int g = 0; g < 16; ++g) {
        float4 lv = lr[g * 16 + ln];                    // elems e = g*64 + ln*4 ..+3
        lsq += lv.x * lv.x + lv.y * lv.y + lv.z * lv.z + lv.w * lv.w;
#pragma unroll
        for (int l = 0; l < 16; ++l) {
            float4 mv = mf[l * 256 + g * 16 + ln];
            cr[l] += lv.x * mv.x + lv.y * mv.y + lv.z * mv.z + lv.w * mv.w;
        }
    }
    // reduce over the 16 lanes of this row (xor masks touch only ln bits)
#pragma unroll
    for (int off = 8; off >= 1; off >>= 1) {
        lsq += __shfl_xor(lsq, off);
#pragma unroll
        for (int l = 0; l < 16; ++l) cr[l] += __shfl_xor(cr[l], off);
    }
    // lane ln emits slot l = ln (static-index select, no scratch)
    float mycr = cr[0];
#pragma unroll
    for (int l = 1; l < 16; ++l) if (ln == l) mycr = cr[l];
    float d2 = lsq + mu_sq[ln] - 2.f * mycr;
    dist[((size_t)(bs * 16 + ln)) * 1024 + n] = sqrtf(fmaxf(d2, 0.f));
}

// ---------------- pack: scores -> softmax -> packed ----------------
// grid = bc*4+h = 512 blocks, 1024 threads.
// PV restructured: wave w -> (j-quarter jg=w>>2, slot-set w&3); lane -> (slot,
// d-quad). V reads are 4-lane-broadcast ds_read_b128; p reads batched uint4
// from bf16 PB (row stride 1032 to avoid slot-set bank conflicts). VST single-
// buffered (16KB) to keep total LDS at the proven ~54KB; next-chunk global
// load issued right after the staging barrier so HBM latency hides under FMAs.
__global__ __launch_bounds__(1024) void k_pack2(const float* __restrict__ kt,
                                                const float* __restrict__ vt,
                                                const float* __restrict__ pq,
                                                const float* __restrict__ dist,
                                                const float* __restrict__ beta_p,
                                                float* __restrict__ packed) {
    int bc = blockIdx.x >> 2, h = blockIdx.x & 3;
    int bs = bc >> 5;                      // bc / C, C==32
    __shared__ __align__(16) float PQ[1024];            // 4KB
    __shared__ __align__(16) ushort_t PB[16 * 1032];    // ~32.3KB padded bf16 p
    __shared__ __align__(16) float VST[4096];           // 16KB: [64][64] v chunk
    __shared__ float wred[16 * 16];
    __shared__ float gred[16];
    int t = threadIdx.x;                   // = n for score phase
    int lane = t & 63, w = t >> 6;         // 16 waves
    PQ[t] = pq[h * 1024 + t];
    float beta = beta_p[0];
    __syncthreads();

    // scores for all 16 slots, accumulated in registers with chunked k-loads
    const size_t base = ((size_t)blockIdx.x) * 65536;  // (bc*4+h)*1024*64
    const float4* kr = (const float4*)(kt + base + (size_t)t * 64);
    float sc[16];
#pragma unroll
    for (int l = 0; l < 16; ++l) sc[l] = 0.f;
    for (int g = 0; g < 16; ++g) {
        float4 kv = kr[g];
#pragma unroll
        for (int l = 0; l < 16; ++l) {
            const float* pql = &PQ[l * 64 + g * 4];
            sc[l] += kv.x * pql[0] + kv.y * pql[1] + kv.z * pql[2] + kv.w * pql[3];
        }
    }
#pragma unroll
    for (int l = 0; l < 16; ++l)
        sc[l] = 0.125f * sc[l] - beta * dist[((size_t)(bs * 16 + l)) * 1024 + t];

    // block-wide max per l
#pragma unroll
    for (int l = 0; l < 16; ++l) {
        float m = sc[l];
#pragma unroll
        for (int off = 32; off >= 1; off >>= 1) m = fmaxf(m, __shfl_xor(m, off));
        if (lane == 0) wred[l * 16 + w] = m;
    }
    __syncthreads();
    if (t < 16) {
        float m = -1e30f;
#pragma unroll
        for (int w2 = 0; w2 < 16; ++w2) m = fmaxf(m, wred[t * 16 + w2]);
        gred[t] = m;
    }
    __syncthreads();

    // exp + block-wide sum per l
    float ex[16];
#pragma unroll
    for (int l = 0; l < 16; ++l) {
        ex[l] = __expf(sc[l] - gred[l]);
        float s = ex[l];
#pragma unroll
        for (int off = 32; off >= 1; off >>= 1) s += __shfl_xor(s, off);
        if (lane == 0) wred[l * 16 + w] = s;
    }
    __syncthreads();
    if (t < 16) {
        float s = 0.f;
#pragma unroll
        for (int w2 = 0; w2 < 16; ++w2) s += wred[t * 16 + w2];
        gred[t] = 1.f / s;
    }
    __syncthreads();
#pragma unroll
    for (int l = 0; l < 16; ++l) PB[l * 1032 + t] = f2bf(ex[l] * gred[l]);

    // ---- PV: packed[l][d] = sum_n p[l][n] * v[n][d] ----
    const float4* vr = (const float4*)(vt + base);
    int jg = w >> 2;                           // this wave's j-quarter within chunk
    int sl = (w & 3) * 4 + (lane >> 4);        // slot 0..15
    int dg = lane & 15;                        // d-quad: d = 4*dg..+3
    float4 acc; acc.x = acc.y = acc.z = acc.w = 0.f;
    float4* VST4 = (float4*)VST;
    float4 pre = vr[t];                        // chunk 0 v-rows
    for (int ch = 0; ch < 16; ++ch) {
        __syncthreads();                       // prior chunk reads done (+PB ready)
        VST4[t] = pre;
        __syncthreads();                       // staging visible
        if (ch < 15) pre = vr[(ch + 1) * 1024 + t];   // issue next load now
        const ushort_t* pbp = &PB[sl * 1032 + ch * 64 + jg * 16];
        uint4 pw0 = *(const uint4*)(pbp);
        uint4 pw1 = *(const uint4*)(pbp + 8);
        const float4* vb = VST4 + jg * 256 + dg;
        unsigned wbuf[8] = {pw0.x, pw0.y, pw0.z, pw0.w, pw1.x, pw1.y, pw1.z, pw1.w};
#pragma unroll
        for (int pr = 0; pr < 8; ++pr) {
            float p0 = __uint_as_float(wbuf[pr] << 16);          // even j
            float p1 = __uint_as_float(wbuf[pr] & 0xffff0000u);  // odd j
            float4 v0 = vb[(2 * pr) * 16];
            float4 v1 = vb[(2 * pr + 1) * 16];
            acc.x += p0 * v0.x + p1 * v1.x;
            acc.y += p0 * v0.y + p1 * v1.y;
            acc.z += p0 * v0.z + p1 * v1.z;
            acc.w += p0 * v0.w + p1 * v1.w;
        }
    }
    __syncthreads();                           // last chunk reads done
    // cross-jg partial reduce through the (dead) VST buffer
    VST4[jg * 256 + sl * 16 + dg] = acc;       // float layout [jg][sl][d]
    __syncthreads();
    int l = t >> 6, d = t & 63;
    float sum = VST[l * 64 + d] + VST[1024 + l * 64 + d]
              + VST[2048 + l * 64 + d] + VST[3072 + l * 64 + d];
    packed[((size_t)blockIdx.x) * 1024 + t] = sum;
}

// ---------------- processed = sdpa(packed, packed, packed) ----------------
__global__ void k_proc(const float* __restrict__ packed, float* __restrict__ proc) {
    int bh = blockIdx.x;           // 512 blocks
    __shared__ float P[1024];
    __shared__ float A[256];
    int t = threadIdx.x;
#pragma unroll
    for (int i = 0; i < 4; ++i) P[t + i * 256] = packed[(size_t)bh * 1024 + t + i * 256];
    __syncthreads();
    {
        int i = t >> 4, j = t & 15;
        float acc = 0.f;
#pragma unroll
        for (int dd = 0; dd < 64; ++dd) acc += P[i * 64 + dd] * P[j * 64 + dd];
        A[t] = acc * 0.125f;
    }
    __syncthreads();
    if (t < 16) {
        float m = -1e30f;
#pragma unroll
        for (int j = 0; j < 16; ++j) m = fmaxf(m, A[t * 16 + j]);
        float s = 0.f;
#pragma unroll
        for (int j = 0; j < 16; ++j) { float e = __expf(A[t * 16 + j] - m); A[t * 16 + j] = e; s += e; }
        float inv = 1.f / s;
#pragma unroll
        for (int j = 0; j < 16; ++j) A[t * 16 + j] *= inv;
    }
    __syncthreads();
#pragma unroll
    for (int i = 0; i < 4; ++i) {
        int e = t + i * 256;
        int r = e >> 6, d = e & 63;
        float acc = 0.f;
#pragma unroll
        for (int j = 0; j < 16; ++j) acc += A[r * 16 + j] * P[j * 64 + d];
        proc[(size_t)bh * 1024 + e] = acc;
    }
}

// ---------------- out = sdpa(q, processed, processed) ----------------
// grid = bh*8+chunk = 4096 blocks, 256 threads. Quad-split: 4 lanes per row
// (16 cols each), 2 rows per thread -> P b128 reads amortized over 2 rows;
// q loads / out stores are one full 64B line per lane.
__global__ __launch_bounds__(256) void k_final(const float* __restrict__ qt,
                                               const float* __restrict__ proc,
                                               float* __restrict__ out) {
    int bh = blockIdx.x >> 3, chunk = blockIdx.x & 7;
    __shared__ __align__(16) float P[1024];
    int t = threadIdx.x;
    ((float4*)P)[t] = ((const float4*)(proc + (size_t)bh * 1024))[t];
    __syncthreads();
    int q = t & 3, rid = t >> 2;
    int n0 = chunk * 128 + rid, n1 = n0 + 64;
    const float4* q0 = (const float4*)(qt + ((size_t)bh * 1024 + n0) * 64) + q * 4;
    const float4* q1 = (const float4*)(qt + ((size_t)bh * 1024 + n1) * 64) + q * 4;
    float4 qa0 = q0[0], qa1 = q0[1], qa2 = q0[2], qa3 = q0[3];
    float4 qb0 = q1[0], qb1 = q1[1], qb2 = q1[2], qb3 = q1[3];
    const float4* P4 = (const float4*)P + q * 4;

    float s0[16], s1[16];
#pragma unroll
    for (int j = 0; j < 16; ++j) {
        float4 p0 = P4[j * 16 + 0], p1 = P4[j * 16 + 1];
        float4 p2 = P4[j * 16 + 2], p3 = P4[j * 16 + 3];
        float a = qa0.x * p0.x + qa0.y * p0.y + qa0.z * p0.z + qa0.w * p0.w
                + qa1.x * p1.x + qa1.y * p1.y + qa1.z * p1.z + qa1.w * p1.w
                + qa2.x * p2.x + qa2.y * p2.y + qa2.z * p2.z + qa2.w * p2.w
                + qa3.x * p3.x + qa3.y * p3.y + qa3.z * p3.z + qa3.w * p3.w;
        float b = qb0.x * p0.x + qb0.y * p0.y + qb0.z * p0.z + qb0.w * p0.w
                + qb1.x * p1.x + qb1.y * p1.y + qb1.z * p1.z + qb1.w * p1.w
                + qb2.x * p2.x + qb2.y * p2.y + qb2.z * p2.z + qb2.w * p2.w
                + qb3.x * p3.x + qb3.y * p3.y + qb3.z * p3.z + qb3.w * p3.w;
        a += __shfl_xor(a, 1); a += __shfl_xor(a, 2);   // reduce over quad
        b += __shfl_xor(b, 1); b += __shfl_xor(b, 2);
        s0[j] = a * 0.125f; s1[j] = b * 0.125f;
    }
    // softmax over 16 keys, per row (replicated across the quad)
    float m0 = s0[0], m1 = s1[0];
#pragma unroll
    for (int j = 1; j < 16; ++j) { m0 = fmaxf(m0, s0[j]); m1 = fmaxf(m1, s1[j]); }
    float t0 = 0.f, t1 = 0.f;
#pragma unroll
    for (int j = 0; j < 16; ++j) {
        s0[j] = __expf(s0[j] - m0); t0 += s0[j];
        s1[j] = __expf(s1[j] - m1); t1 += s1[j];
    }
    float i0 = 1.f / t0, i1 = 1.f / t1;
#pragma unroll
    for (int j = 0; j < 16; ++j) { s0[j] *= i0; s1[j] *= i1; }

    float4 o00, o01, o02, o03, o10, o11, o12, o13;
    o00.x=o00.y=o00.z=o00.w=0.f; o01=o00; o02=o00; o03=o00;
    o10=o00; o11=o00; o12=o00; o13=o00;
#pragma unroll
    for (int j = 0; j < 16; ++j) {
        float4 p0 = P4[j * 16 + 0], p1 = P4[j * 16 + 1];
        float4 p2 = P4[j * 16 + 2], p3 = P4[j * 16 + 3];
        float a = s0[j], b = s1[j];
        o00.x += a * p0.x; o00.y += a * p0.y; o00.z += a * p0.z; o00.w += a * p0.w;
        o01.x += a * p1.x; o01.y += a * p1.y; o01.z += a * p1.z; o01.w += a * p1.w;
        o02.x += a * p2.x; o02.y += a * p2.y; o02.z += a * p2.z; o02.w += a * p2.w;
        o03.x += a * p3.x; o03.y += a * p3.y; o03.z += a * p3.z; o03.w += a * p3.w;
        o10.x += b * p0.x; o10.y += b * p0.y; o10.z += b * p0.z; o10.w += b * p0.w;
        o11.x += b * p1.x; o11.y += b * p1.y; o11.z += b * p1.z; o11.w += b * p1.w;
        o12.x += b * p2.x; o12.y += b * p2.y; o12.z += b * p2.z; o12.w += b * p2.w;
        o13.x += b * p3.x; o13.y += b * p3.y; o13.z += b * p3.z; o13.w += b * p3.w;
    }
    float4* w0 = (float4*)(out + ((size_t)bh * 1024 + n0) * 64) + q * 4;
    float4* w1 = (float4*)(out + ((size_t)bh * 1024 + n1) * 64) + q * 4;
    w0[0] = o00; w0[1] = o01; w0[2] = o02; w0[3] = o03;
    w1[0] = o10; w1[1] = o11; w1[2] = o12; w1[3] = o13;
}

extern "C" void kernel_launch(void* const* d_in, const int* in_sizes, int n_in,
                              void* d_out, int out_size, void* d_ws, size_t ws_size,
                              hipStream_t stream) {
    const float* q     = (const float*)d_in[0];
    const float* k     = (const float*)d_in[1];
    const float* v     = (const float*)d_in[2];
    const float* Ln    = (const float*)d_in[3];
    const float* slots = (const float*)d_in[4];
    const float* W     = (const float*)d_in[5];
    const float* mu    = (const float*)d_in[6];
    const float* beta  = (const float*)d_in[7];
    const int* cidx    = (const int*)d_in[8];
    // d_in[9] is C (==32), hard-coded in kernels.

    float* ws     = (float*)d_ws;
    float* pq     = ws;                 //   4096 f32
    float* muf    = ws + 4096;          //  16384 f32
    float* musq   = ws + 20480;         //     16 f32
    float* dist   = ws + 20496;         //  65536 f32
    float* packed = ws + 86032;         // 524288 f32
    float* proc   = ws + 610320;        // 524288 f32  (total ~4.5 MB)

    k_pq   <<<16,   256, 0, stream>>>(slots, W, pq);
    k_mu   <<<16,   256, 0, stream>>>(mu, cidx, muf, musq);
    k_dist <<<256,  256, 0, stream>>>(Ln, muf, musq, dist);
    k_pack2<<<512, 1024, 0, stream>>>(k, v, pq, dist, beta, packed);
    k_proc <<<512,  256, 0, stream>>>(packed, proc);
    k_final<<<4096, 256, 0, stream>>>(q, proc, (float*)d_out);
}

// Round 4
// 599.609 us; speedup vs baseline: 1.0675x; 1.0011x over previous
//
#include <hip/hip_runtime.h>
#include <hip/hip_bf16.h>

// Shapes (fixed by setup_inputs): BC=128, H=4, N=1024, d=64, l=16, B=4, C=32,
// C_ch=32, TC=144, r=8. All float tensors are FLOAT32 (per reference).
typedef unsigned short ushort_t;

__device__ __forceinline__ float bf2f(ushort_t u) {
    return __uint_as_float(((unsigned int)u) << 16);
}
__device__ __forceinline__ ushort_t f2bf(float f) {
    __hip_bfloat16 h = __float2bfloat16(f);
    return *reinterpret_cast<ushort_t*>(&h);
}

// ---------------- pq = slots[0] @ W^T, reshaped to [h][l][d] ----------------
// grid = 16 (one block per slot l), 256 threads (j = h*64+d)
__global__ __launch_bounds__(256) void k_pq(const float* __restrict__ slots,
                                            const float* __restrict__ W,
                                            float* __restrict__ pq) {
    int l = blockIdx.x, j = threadIdx.x;
    __shared__ float SL[256];
    SL[j] = slots[l * 256 + j];
    __syncthreads();
    const float4* wr = (const float4*)(W + j * 256);
    float acc = 0.f;
#pragma unroll 8
    for (int g = 0; g < 64; ++g) {
        float4 wv = wr[g];
        const float* sl = &SL[g * 4];
        acc += wv.x * sl[0] + wv.y * sl[1] + wv.z * sl[2] + wv.w * sl[3];
    }
    int h = j >> 6, d = j & 63;
    pq[(h * 16 + l) * 64 + d] = acc;
}

// ---------------- mu_flat[l][c*32+dd], mu_sqnorm[l] ----------------
__global__ void k_mu(const float* __restrict__ mu,
                     const int* __restrict__ cidx,
                     float* __restrict__ mu_flat,
                     float* __restrict__ mu_sq) {
    int l = blockIdx.x;            // 16 blocks
    __shared__ float U[256];       // [c][r] 32x8
    __shared__ float utu[64];
    int t = threadIdx.x;
    {
        int c = t >> 3, r = t & 7;
        U[t] = mu[(l * 144 + cidx[c]) * 8 + r];
    }
    __syncthreads();
#pragma unroll
    for (int i = 0; i < 4; ++i) {
        int e = t + i * 256;
        int c = e >> 5, dd = e & 31;
        float acc = 0.f;
#pragma unroll
        for (int r = 0; r < 8; ++r) acc += U[c * 8 + r] * U[dd * 8 + r];
        mu_flat[l * 1024 + e] = acc;
    }
    if (t < 64) {
        int r = t >> 3, s = t & 7;
        float acc = 0.f;
        for (int c = 0; c < 32; ++c) acc += U[c * 8 + r] * U[c * 8 + s];
        utu[t] = acc;
    }
    __syncthreads();
    if (t == 0) {
        float acc = 0.f;
        for (int i = 0; i < 64; ++i) acc += utu[i] * utu[i];
        mu_sq[l] = acc;
    }
}

// ---------------- dist[bs][l][n] ----------------
// grid = 256: bs = blk>>6, nchunk = blk&63. 256 threads: 16 rows x 16 lanes/row.
// No LDS: mu_flat (64KB) is L2-resident and each float4 read is a 4-way
// intra-wave broadcast, so global reads through L1/L2 are cheap.
__global__ __launch_bounds__(256) void k_dist(const float* __restrict__ Ln,
                                              const float* __restrict__ mu_flat,
                                              const float* __restrict__ mu_sq,
                                              float* __restrict__ dist) {
    int blk = blockIdx.x;
    int nchunk = blk & 63, bs = blk >> 6;
    int t = threadIdx.x;
    int ln = t & 15, rid = t >> 4;
    int n = nchunk * 16 + rid;
    const float4* lr = (const float4*)(Ln + ((size_t)(bs * 1024 + n)) * 1024);
    const float4* mf = (const float4*)mu_flat;
    float lsq = 0.f;
    float cr[16];
#pragma unroll
    for (int l = 0; l < 16; ++l) cr[l] = 0.f;
#pragma unroll 2
    for (int g = 0; g < 16; ++g) {
        float4 lv = lr[g * 16 + ln];                    // elems e = g*64 + ln*4 ..+3
        lsq += lv.x * lv.x + lv.y * lv.y + lv.z * lv.z + lv.w * lv.w;
#pragma unroll
        for (int l = 0; l < 16; ++l) {
            float4 mv = mf[l * 256 + g * 16 + ln];
            cr[l] += lv.x * mv.x + lv.y * mv.y + lv.z * mv.z + lv.w * mv.w;
        }
    }
    // reduce over the 16 lanes of this row (xor masks touch only ln bits)
#pragma unroll
    for (int off = 8; off >= 1; off >>= 1) {
        lsq += __shfl_xor(lsq, off);
#pragma unroll
        for (int l = 0; l < 16; ++l) cr[l] += __shfl_xor(cr[l], off);
    }
    // lane ln emits slot l = ln (static-index select, no scratch)
    float mycr = cr[0];
#pragma unroll
    for (int l = 1; l < 16; ++l) if (ln == l) mycr = cr[l];
    float d2 = lsq + mu_sq[ln] - 2.f * mycr;
    dist[((size_t)(bs * 16 + ln)) * 1024 + n] = sqrtf(fmaxf(d2, 0.f));
}

// ---------------- pack: scores -> softmax -> packed ----------------
// grid = bc*4+h = 512 blocks, 1024 threads.
// PV: barrier-free. Wave w -> (j-quarter jg=w>>2, slot-set w&3); lane ->
// (slot sl, d-quad dg). p read from LDS PB (bf16, batched uint4, stride 1032);
// V streamed DIRECTLY from global: at fixed (jg,j) the 4 sl-groups read the
// same 256B row segment (2 cache lines, lane-broadcast), and the 4 waves
// sharing jg hit the same lines in L1 -> no LDS staging, no per-chunk
// barriers, no vmcnt drains. Loads batched 8-deep for memory-level parallelism.
__global__ __launch_bounds__(1024) void k_pack2(const float* __restrict__ kt,
                                                const float* __restrict__ vt,
                                                const float* __restrict__ pq,
                                                const float* __restrict__ dist,
                                                const float* __restrict__ beta_p,
                                                float* __restrict__ packed) {
    int bc = blockIdx.x >> 2, h = blockIdx.x & 3;
    int bs = bc >> 5;                      // bc / C, C==32
    __shared__ __align__(16) float PQ[1024];            // 4KB
    __shared__ __align__(16) ushort_t PB[16 * 1032];    // ~32.3KB padded bf16 p
    __shared__ __align__(16) float RED[4096];           // 16KB cross-jg reduce
    __shared__ float wred[16 * 16];
    __shared__ float gred[16];
    int t = threadIdx.x;                   // = n for score phase
    int lane = t & 63, w = t >> 6;         // 16 waves
    PQ[t] = pq[h * 1024 + t];
    float beta = beta_p[0];
    __syncthreads();

    // scores for all 16 slots, accumulated in registers with chunked k-loads
    const size_t base = ((size_t)blockIdx.x) * 65536;  // (bc*4+h)*1024*64
    const float4* kr = (const float4*)(kt + base + (size_t)t * 64);
    float sc[16];
#pragma unroll
    for (int l = 0; l < 16; ++l) sc[l] = 0.f;
    for (int g = 0; g < 16; ++g) {
        float4 kv = kr[g];
#pragma unroll
        for (int l = 0; l < 16; ++l) {
            const float* pql = &PQ[l * 64 + g * 4];
            sc[l] += kv.x * pql[0] + kv.y * pql[1] + kv.z * pql[2] + kv.w * pql[3];
        }
    }
#pragma unroll
    for (int l = 0; l < 16; ++l)
        sc[l] = 0.125f * sc[l] - beta * dist[((size_t)(bs * 16 + l)) * 1024 + t];

    // block-wide max per l
#pragma unroll
    for (int l = 0; l < 16; ++l) {
        float m = sc[l];
#pragma unroll
        for (int off = 32; off >= 1; off >>= 1) m = fmaxf(m, __shfl_xor(m, off));
        if (lane == 0) wred[l * 16 + w] = m;
    }
    __syncthreads();
    if (t < 16) {
        float m = -1e30f;
#pragma unroll
        for (int w2 = 0; w2 < 16; ++w2) m = fmaxf(m, wred[t * 16 + w2]);
        gred[t] = m;
    }
    __syncthreads();

    // exp + block-wide sum per l
    float ex[16];
#pragma unroll
    for (int l = 0; l < 16; ++l) {
        ex[l] = __expf(sc[l] - gred[l]);
        float s = ex[l];
#pragma unroll
        for (int off = 32; off >= 1; off >>= 1) s += __shfl_xor(s, off);
        if (lane == 0) wred[l * 16 + w] = s;
    }
    __syncthreads();
    if (t < 16) {
        float s = 0.f;
#pragma unroll
        for (int w2 = 0; w2 < 16; ++w2) s += wred[t * 16 + w2];
        gred[t] = 1.f / s;
    }
    __syncthreads();
#pragma unroll
    for (int l = 0; l < 16; ++l) PB[l * 1032 + t] = f2bf(ex[l] * gred[l]);
    __syncthreads();                        // PB visible to all waves

    // ---- PV: packed[l][d] = sum_n p[l][n] * v[n][d], barrier-free ----
    const float4* vr4 = (const float4*)(vt + base);
    int jg = w >> 2;                           // this wave's j-quarter
    int sl = (w & 3) * 4 + (lane >> 4);        // slot 0..15
    int dg = lane & 15;                        // d-quad: d = 4*dg..+3
    float4 acc; acc.x = acc.y = acc.z = acc.w = 0.f;
    for (int ch = 0; ch < 16; ++ch) {
        const ushort_t* pbp = &PB[sl * 1032 + ch * 64 + jg * 16];
        uint4 pw0 = *(const uint4*)(pbp);
        uint4 pw1 = *(const uint4*)(pbp + 8);
        const float4* vg = vr4 + (size_t)(ch * 64 + jg * 16) * 16 + dg;
        unsigned wb0[4] = {pw0.x, pw0.y, pw0.z, pw0.w};
        unsigned wb1[4] = {pw1.x, pw1.y, pw1.z, pw1.w};
        float4 vld[8];
#pragma unroll
        for (int j = 0; j < 8; ++j) vld[j] = vg[j * 16];
#pragma unroll
        for (int pr = 0; pr < 4; ++pr) {
            float p0 = __uint_as_float(wb0[pr] << 16);           // even j
            float p1 = __uint_as_float(wb0[pr] & 0xffff0000u);   // odd j
            float4 v0 = vld[2 * pr], v1 = vld[2 * pr + 1];
            acc.x += p0 * v0.x + p1 * v1.x;
            acc.y += p0 * v0.y + p1 * v1.y;
            acc.z += p0 * v0.z + p1 * v1.z;
            acc.w += p0 * v0.w + p1 * v1.w;
        }
#pragma unroll
        for (int j = 0; j < 8; ++j) vld[j] = vg[(8 + j) * 16];
#pragma unroll
        for (int pr = 0; pr < 4; ++pr) {
            float p0 = __uint_as_float(wb1[pr] << 16);           // even j
            float p1 = __uint_as_float(wb1[pr] & 0xffff0000u);   // odd j
            float4 v0 = vld[2 * pr], v1 = vld[2 * pr + 1];
            acc.x += p0 * v0.x + p1 * v1.x;
            acc.y += p0 * v0.y + p1 * v1.y;
            acc.z += p0 * v0.z + p1 * v1.z;
            acc.w += p0 * v0.w + p1 * v1.w;
        }
    }
    // cross-jg partial reduce through RED
    ((float4*)RED)[jg * 256 + sl * 16 + dg] = acc;   // float layout [jg][sl][d]
    __syncthreads();
    int l = t >> 6, d = t & 63;
    float sum = RED[l * 64 + d] + RED[1024 + l * 64 + d]
              + RED[2048 + l * 64 + d] + RED[3072 + l * 64 + d];
    packed[((size_t)blockIdx.x) * 1024 + t] = sum;
}

// ---------------- processed = sdpa(packed, packed, packed) ----------------
__global__ void k_proc(const float* __restrict__ packed, float* __restrict__ proc) {
    int bh = blockIdx.x;           // 512 blocks
    __shared__ float P[1024];
    __shared__ float A[256];
    int t = threadIdx.x;
#pragma unroll
    for (int i = 0; i < 4; ++i) P[t + i * 256] = packed[(size_t)bh * 1024 + t + i * 256];
    __syncthreads();
    {
        int i = t >> 4, j = t & 15;
        float acc = 0.f;
#pragma unroll
        for (int dd = 0; dd < 64; ++dd) acc += P[i * 64 + dd] * P[j * 64 + dd];
        A[t] = acc * 0.125f;
    }
    __syncthreads();
    if (t < 16) {
        float m = -1e30f;
#pragma unroll
        for (int j = 0; j < 16; ++j) m = fmaxf(m, A[t * 16 + j]);
        float s = 0.f;
#pragma unroll
        for (int j = 0; j < 16; ++j) { float e = __expf(A[t * 16 + j] - m); A[t * 16 + j] = e; s += e; }
        float inv = 1.f / s;
#pragma unroll
        for (int j = 0; j < 16; ++j) A[t * 16 + j] *= inv;
    }
    __syncthreads();
#pragma unroll
    for (int i = 0; i < 4; ++i) {
        int e = t + i * 256;
        int r = e >> 6, d = e & 63;
        float acc = 0.f;
#pragma unroll
        for (int j = 0; j < 16; ++j) acc += A[r * 16 + j] * P[j * 64 + d];
        proc[(size_t)bh * 1024 + e] = acc;
    }
}

// ---------------- out = sdpa(q, processed, processed) ----------------
// grid = bh*8+chunk = 4096 blocks, 256 threads. Quad-split: 4 lanes per row
// (16 cols each), 2 rows per thread -> P b128 reads amortized over 2 rows;
// q loads / out stores are one full 64B line per lane.
__global__ __launch_bounds__(256) void k_final(const float* __restrict__ qt,
                                               const float* __restrict__ proc,
                                               float* __restrict__ out) {
    int bh = blockIdx.x >> 3, chunk = blockIdx.x & 7;
    __shared__ __align__(16) float P[1024];
    int t = threadIdx.x;
    ((float4*)P)[t] = ((const float4*)(proc + (size_t)bh * 1024))[t];
    __syncthreads();
    int q = t & 3, rid = t >> 2;
    int n0 = chunk * 128 + rid, n1 = n0 + 64;
    const float4* q0 = (const float4*)(qt + ((size_t)bh * 1024 + n0) * 64) + q * 4;
    const float4* q1 = (const float4*)(qt + ((size_t)bh * 1024 + n1) * 64) + q * 4;
    float4 qa0 = q0[0], qa1 = q0[1], qa2 = q0[2], qa3 = q0[3];
    float4 qb0 = q1[0], qb1 = q1[1], qb2 = q1[2], qb3 = q1[3];
    const float4* P4 = (const float4*)P + q * 4;

    float s0[16], s1[16];
#pragma unroll
    for (int j = 0; j < 16; ++j) {
        float4 p0 = P4[j * 16 + 0], p1 = P4[j * 16 + 1];
        float4 p2 = P4[j * 16 + 2], p3 = P4[j * 16 + 3];
        float a = qa0.x * p0.x + qa0.y * p0.y + qa0.z * p0.z + qa0.w * p0.w
                + qa1.x * p1.x + qa1.y * p1.y + qa1.z * p1.z + qa1.w * p1.w
                + qa2.x * p2.x + qa2.y * p2.y + qa2.z * p2.z + qa2.w * p2.w
                + qa3.x * p3.x + qa3.y * p3.y + qa3.z * p3.z + qa3.w * p3.w;
        float b = qb0.x * p0.x + qb0.y * p0.y + qb0.z * p0.z + qb0.w * p0.w
                + qb1.x * p1.x + qb1.y * p1.y + qb1.z * p1.z + qb1.w * p1.w
                + qb2.x * p2.x + qb2.y * p2.y + qb2.z * p2.z + qb2.w * p2.w
                + qb3.x * p3.x + qb3.y * p3.y + qb3.z * p3.z + qb3.w * p3.w;
        a += __shfl_xor(a, 1); a += __shfl_xor(a, 2);   // reduce over quad
        b += __shfl_xor(b, 1); b += __shfl_xor(b, 2);
        s0[j] = a * 0.125f; s1[j] = b * 0.125f;
    }
    // softmax over 16 keys, per row (replicated across the quad)
    float m0 = s0[0], m1 = s1[0];
#pragma unroll
    for (int j = 1; j < 16; ++j) { m0 = fmaxf(m0, s0[j]); m1 = fmaxf(m1, s1[j]); }
    float t0 = 0.f, t1 = 0.f;
#pragma unroll
    for (int j = 0; j < 16; ++j) {
        s0[j] = __expf(s0[j] - m0); t0 += s0[j];
        s1[j] = __expf(s1[j] - m1); t1 += s1[j];
    }
    float i0 = 1.f / t0, i1 = 1.f / t1;
#pragma unroll
    for (int j = 0; j < 16; ++j) { s0[j] *= i0; s1[j] *= i1; }

    float4 o00, o01, o02, o03, o10, o11, o12, o13;
    o00.x=o00.y=o00.z=o00.w=0.f; o01=o00; o02=o00; o03=o00;
    o10=o00; o11=o00; o12=o00; o13=o00;
#pragma unroll
    for (int j = 0; j < 16; ++j) {
        float4 p0 = P4[j * 16 + 0], p1 = P4[j * 16 + 1];
        float4 p2 = P4[j * 16 + 2], p3 = P4[j * 16 + 3];
        float a = s0[j], b = s1[j];
        o00.x += a * p0.x; o00.y += a * p0.y; o00.z += a * p0.z; o00.w += a * p0.w;
        o01.x += a * p1.x; o01.y += a * p1.y; o01.z += a * p1.z; o01.w += a * p1.w;
        o02.x += a * p2.x; o02.y += a * p2.y; o02.z += a * p2.z; o02.w += a * p2.w;
        o03.x += a * p3.x; o03.y += a * p3.y; o03.z += a * p3.z; o03.w += a * p3.w;
        o10.x += b * p0.x; o10.y += b * p0.y; o10.z += b * p0.z; o10.w += b * p0.w;
        o11.x += b * p1.x; o11.y += b * p1.y; o11.z += b * p1.z; o11.w += b * p1.w;
        o12.x += b * p2.x; o12.y += b * p2.y; o12.z += b * p2.z; o12.w += b * p2.w;
        o13.x += b * p3.x; o13.y += b * p3.y; o13.z += b * p3.z; o13.w += b * p3.w;
    }
    float4* w0 = (float4*)(out + ((size_t)bh * 1024 + n0) * 64) + q * 4;
    float4* w1 = (float4*)(out + ((size_t)bh * 1024 + n1) * 64) + q * 4;
    w0[0] = o00; w0[1] = o01; w0[2] = o02; w0[3] = o03;
    w1[0] = o10; w1[1] = o11; w1[2] = o12; w1[3] = o13;
}

extern "C" void kernel_launch(void* const* d_in, const int* in_sizes, int n_in,
                              void* d_out, int out_size, void* d_ws, size_t ws_size,
                              hipStream_t stream) {
    const float* q     = (const float*)d_in[0];
    const float* k     = (const float*)d_in[1];
    const float* v     = (const float*)d_in[2];
    const float* Ln    = (const float*)d_in[3];
    const float* slots = (const float*)d_in[4];
    const float* W     = (const float*)d_in[5];
    const float* mu    = (const float*)d_in[6];
    const float* beta  = (const float*)d_in[7];
    const int* cidx    = (const int*)d_in[8];
    // d_in[9] is C (==32), hard-coded in kernels.

    float* ws     = (float*)d_ws;
    float* pq     = ws;                 //   4096 f32
    float* muf    = ws + 4096;          //  16384 f32
    float* musq   = ws + 20480;         //     16 f32
    float* dist   = ws + 20496;         //  65536 f32
    float* packed = ws + 86032;         // 524288 f32
    float* proc   = ws + 610320;        // 524288 f32  (total ~4.5 MB)

    k_pq   <<<16,   256, 0, stream>>>(slots, W, pq);
    k_mu   <<<16,   256, 0, stream>>>(mu, cidx, muf, musq);
    k_dist <<<256,  256, 0, stream>>>(Ln, muf, musq, dist);
    k_pack2<<<512, 1024, 0, stream>>>(k, v, pq, dist, beta, packed);
    k_proc <<<512,  256, 0, stream>>>(packed, proc);
    k_final<<<4096, 256, 0, stream>>>(q, proc, (float*)d_out);
}